// Round 26
// baseline (1260.475 us; speedup 1.0000x reference)
//
#include <hip/hip_runtime.h>
#include <hip/hip_bf16.h>
#include <math.h>

// ---------------------------------------------------------------------------
// GraphEncoder round 26: r25 (best: 1257us) + final setup-path crumbs:
//  (1) deg zeroing fused into conv_x (drops one dispatch)
//  (2) pool group bounds precomputed once (pool_bounds, 17 blocks) instead of
//      2x 17-iter binary searches per pool_mean wave. Identical values.
// Everything else identical to r25: BM=256 depth-2 counted-vmcnt MFMA GEMM
// (~186us plateau; remaining lever is the 8-phase rewrite, out of
// single-shot risk budget), 8-wide gat_fused, lin0->rnn0 fold, div-free
// conversions, hierarchical scan. Session: 14009us (r3) -> 1257us (r25).
// ---------------------------------------------------------------------------

constexpr int NN    = 100000;
constexpr int EE    = 400000;
constexpr int EP    = EE + NN;      // 500000 (incl self loops)
constexpr int BG    = 4096;
constexpr int FIN   = 300;
constexpr int HEADS = 4;
constexpr int HID   = 256;
constexpr int G4H   = 1024;
constexpr int NH1   = 512;
constexpr int NH2   = 768;
constexpr int MP    = 100352;       // 392*256, 392 % 8 == 0
constexpr int KP0   = 320;          // FIN padded to mult of 32
constexpr int SCB   = 392;          // scan blocks (392*256 = 100352 >= NN)

typedef __attribute__((ext_vector_type(4))) float f32x4;
typedef __attribute__((ext_vector_type(8))) short s16x8;
typedef __attribute__((ext_vector_type(4))) short s16x4;

#define LOG2E 1.4426950408889634f

// fast HW transcendentals (v_exp_f32 = 2^x, v_rcp_f32)
__device__ inline float fexp(float x)  { return __builtin_amdgcn_exp2f(x * LOG2E); }
__device__ inline float frcp(float x)  { return __builtin_amdgcn_rcpf(x); }
__device__ inline float fsigm(float x) { return frcp(1.f + __builtin_amdgcn_exp2f(-LOG2E * x)); }
__device__ inline float ftanh(float x) { return 1.f - 2.f * frcp(1.f + __builtin_amdgcn_exp2f(2.f * LOG2E * x)); }

__device__ inline float b2f(short s) { return __uint_as_float(((unsigned)(unsigned short)s) << 16); }
__device__ inline short f2b(float f) {
    unsigned u = __float_as_uint(f);
    u += 0x7fff + ((u >> 16) & 1);          // round-to-nearest-even
    return (short)(u >> 16);
}
__device__ inline float wsum64(float v) {
#pragma unroll
    for (int o = 32; o > 0; o >>= 1) v += __shfl_xor(v, o);
    return v;
}

// ---------------- setup kernels ---------------------------------------------
// x pad-convert without divisions: 8 rows/block, threads stride the 320 cols.
// Also zeroes deg[] (blocks 0..391 cover NN) - saves a dispatch.
__global__ __launch_bounds__(256) void conv_x(
    const float* __restrict__ src, short* __restrict__ dst,
    int* __restrict__ deg)
{
    int z = blockIdx.x * 256 + threadIdx.x;
    if (z < NN) deg[z] = 0;
    int r0 = blockIdx.x * 8;
#pragma unroll
    for (int rr = 0; rr < 8; ++rr) {
        int r = r0 + rr;
        const float* s = src + (size_t)r * FIN;
        short* d = dst + (size_t)r * KP0;
        bool valid = (r < NN);
        for (int c = threadIdx.x; c < KP0; c += 256) {
            float v = (valid && c < FIN) ? s[c] : 0.f;
            d[c] = f2b(v);
        }
    }
}

// ---- batched weight conversions: one dispatch for all small tensors --------
// Row-per-block loops (no per-element division).
// gate==0: pad-convert [rsrc x Ks] -> [rows x Kd] bf16
// gate==1: gate-interleaved LSTM pack, rows=1024, Ks=Kd=256
struct CDesc { const float* src; short* dst; int rows, Ks, Kd, rsrc, gate; };
struct CPack { CDesc d[16]; };

__global__ __launch_bounds__(256) void conv_pack(CPack p, int nd)
{
    int di = blockIdx.y;
    if (di >= nd) return;
    CDesc c = p.d[di];
    for (int r = blockIdx.x; r < c.rows; r += gridDim.x) {
        short* d = c.dst + (size_t)r * c.Kd;
        if (c.gate) {
            int gate = (r >> 4) & 3;
            int ch   = (r >> 7) * 32 + ((r >> 6) & 1) * 16 + (r & 15);
            const float* s = c.src + (size_t)(gate * 256 + ch) * c.Ks;
            for (int k = threadIdx.x; k < c.Kd; k += 256)
                d[k] = f2b(s[k]);
        } else {
            const float* s = c.src + (size_t)r * c.Ks;
            bool valid = (r < c.rsrc);
            for (int k = threadIdx.x; k < c.Kd; k += 256) {
                float v = (valid && k < c.Ks) ? s[k] : 0.f;
                d[k] = f2b(v);
            }
        }
    }
}

// ---- lin0->rnn0 fold: W'[packed p][k] = sum_h r0_wih[orig][h]*lin0_w[h][k] --
// one block per packed row p (gate-interleaved dest); 320 threads = cols.
__global__ __launch_bounds__(320) void fold_w(
    const float* __restrict__ wih, const float* __restrict__ lw,
    short* __restrict__ dst)
{
    __shared__ float row[256];
    int p = blockIdx.x;
    int gate = (p >> 4) & 3;
    int ch   = (p >> 7) * 32 + ((p >> 6) & 1) * 16 + (p & 15);
    int orig = gate * 256 + ch;
    for (int h = threadIdx.x; h < 256; h += 320)
        row[h] = wih[(size_t)orig * 256 + h];
    __syncthreads();
    int j = threadIdx.x;                 // 0..319
    float s = 0.f;
    if (j < FIN) {
        for (int h = 0; h < 256; ++h) s += row[h] * lw[(size_t)h * FIN + j];
    }
    dst[(size_t)p * KP0 + j] = f2b(s);
}

// b'[orig t] = r0_bih[t] + r0_bhh[t] + sum_h r0_wih[t][h]*lin0_b[h]
__global__ __launch_bounds__(256) void fold_b(
    const float* __restrict__ wih, const float* __restrict__ lb,
    const float* __restrict__ bih, const float* __restrict__ bhh,
    float* __restrict__ dst)
{
    int t = blockIdx.x * 256 + threadIdx.x;
    if (t >= G4H) return;
    float s = bih[t] + bhh[t];
    for (int h = 0; h < 256; ++h) s += wih[(size_t)t * 256 + h] * lb[h];
    dst[t] = s;
}

// ---- batched bias concat (3 layers x [bl|br] -> blr f32[512]) --------------
struct BPack { const float* a[3]; const float* b[3]; float* dst[3]; };
__global__ __launch_bounds__(256) void concat_pack(BPack p)
{
    int l = blockIdx.x >> 1;
    int half = blockIdx.x & 1;
    const float* s = half ? p.b[l] : p.a[l];
    p.dst[l][half * 256 + threadIdx.x] = s[threadIdx.x];
}

// ---- pool group bounds: gbnd[b] = lower_bound(batch, b); gbnd[BG] = NN -----
__global__ __launch_bounds__(256) void pool_bounds(const int* __restrict__ batch,
                                                   int* __restrict__ gbnd)
{
    int b = blockIdx.x * 256 + threadIdx.x;
    if (b > BG) return;
    if (b == BG) { gbnd[BG] = NN; return; }
    int lo = 0, hi = NN;
    while (lo < hi) { int mid = (lo + hi) >> 1; if (batch[mid] < b) lo = mid + 1; else hi = mid; }
    gbnd[b] = lo;
}

// ---------------- CSR build -------------------------------------------------
__global__ __launch_bounds__(256) void edge_hist(const int* __restrict__ ei,
                                                 int* __restrict__ deg)
{
    int e = blockIdx.x * 256 + threadIdx.x;
    if (e >= EP) return;
    int d = (e < EE) ? ei[EE + e] : e - EE;
    atomicAdd(&deg[d], 1);
}

// pass 1: per-block chunk sums (coalesced)
__global__ __launch_bounds__(256) void scan_part(const int* __restrict__ deg,
                                                 int* __restrict__ bsum)
{
    int b = blockIdx.x, t = threadIdx.x;
    int i = b * 256 + t;
    int v = (i < NN) ? deg[i] : 0;
#pragma unroll
    for (int o = 32; o > 0; o >>= 1) v += __shfl_down(v, o);
    __shared__ int sh[4];
    if ((t & 63) == 0) sh[t >> 6] = v;
    __syncthreads();
    if (t == 0) bsum[b] = sh[0] + sh[1] + sh[2] + sh[3];
}

// pass 2: scan the 392 block sums (single small block)
__global__ __launch_bounds__(512) void scan_tops(const int* __restrict__ bsum,
                                                 int* __restrict__ bpre,
                                                 int* __restrict__ rowptr)
{
    __shared__ int sh[512];
    int t = threadIdx.x;
    int v = (t < SCB) ? bsum[t] : 0;
    sh[t] = v;
    __syncthreads();
    for (int off = 1; off < 512; off <<= 1) {
        int u = (t >= off) ? sh[t - off] : 0;
        __syncthreads();
        sh[t] += u;
        __syncthreads();
    }
    if (t < SCB) bpre[t] = sh[t] - v;          // exclusive prefix
    if (t == SCB - 1) rowptr[NN] = sh[t];      // total == EP
}

// pass 3: intra-block exclusive scan + write rowptr/cursor (coalesced)
__global__ __launch_bounds__(256) void scan_fill(const int* __restrict__ deg,
                                                 const int* __restrict__ bpre,
                                                 int* __restrict__ rowptr,
                                                 int* __restrict__ cursor)
{
    __shared__ int sh[256];
    int b = blockIdx.x, t = threadIdx.x;
    int i = b * 256 + t;
    int v = (i < NN) ? deg[i] : 0;
    sh[t] = v;
    __syncthreads();
    for (int off = 1; off < 256; off <<= 1) {
        int u = (t >= off) ? sh[t - off] : 0;
        __syncthreads();
        sh[t] += u;
        __syncthreads();
    }
    if (i < NN) {
        rowptr[i] = bpre[b] + sh[t] - v;       // exclusive
        cursor[i] = 0;
    }
}

__global__ __launch_bounds__(256) void edge_fill(const int* __restrict__ ei,
                                                 const int* __restrict__ rowptr,
                                                 int* __restrict__ cursor,
                                                 int* __restrict__ esrc)
{
    int e = blockIdx.x * 256 + threadIdx.x;
    if (e >= EP) return;
    int s, d;
    if (e < EE) { s = ei[e]; d = ei[EE + e]; }
    else        { s = d = e - EE; }
    int slot = rowptr[d] + atomicAdd(&cursor[d], 1);
    esrc[slot] = s;
}

// ---------------- MFMA GEMM with fused epilogues ----------------------------
// (identical schedule to r17/r19-r25)
__global__ __launch_bounds__(512) void mfma_gemm(
    const short* __restrict__ A1, const short* __restrict__ B1, int K1,
    const short* __restrict__ A2, const short* __restrict__ B2, int K2,
    const float* __restrict__ bias,
    const float* __restrict__ bih, const float* __restrict__ bhh,
    const float* __restrict__ c_in, float* __restrict__ c_out,
    short* __restrict__ h_out,
    float* __restrict__ Cf, short* __restrict__ Cb, int N, int mode, int nct)
{
    __shared__ __align__(16) short sA[2][256 * 32];   // 16KB each
    __shared__ __align__(16) short sB[2][128 * 32];   // 8KB each
    const int tid  = threadIdx.x;
    const int w    = tid >> 6, lane = tid & 63;
    const int wr   = w >> 1,  wc   = w & 1;      // 4x2 waves of 64x64
    // XCD-aware decode (consecutive bids round-robin across 8 XCDs)
    const int bid  = blockIdx.x;
    const int xcd  = bid & 7;
    const int slot = bid >> 3;
    const int g    = slot / nct;
    const int tcol = slot - g * nct;
    const int row0 = (g * 8 + xcd) * 256;
    const int col0 = tcol * 128;

    f32x4 acc[4][4];
#pragma unroll
    for (int m = 0; m < 4; ++m)
#pragma unroll
        for (int n = 0; n < 4; ++n) acc[m][n] = (f32x4){0.f, 0.f, 0.f, 0.f};

    const int rs = lane >> 2;
    const int cs = lane & 3;
    const int KK = K1 + K2;
    const int nsteps = KK >> 5;
    const int l16 = lane & 15;
    const int rloc = wr * 64 + ((lane >> 4) << 2);   // block-local base row

    // mode-2: prefetch c_in into regs; latency hides under the K-loop
    float co_pre[4][4] = {};
    const int ch = tcol * 32 + wc * 16 + l16;        // mode-2 channel
    if (mode == 2 && c_in) {
#pragma unroll
        for (int m = 0; m < 4; ++m)
#pragma unroll
            for (int r = 0; r < 4; ++r)
                co_pre[m][r] = c_in[(size_t)(row0 + rloc + m * 16 + r) * HID + ch];
    }

    // 3 global_load_lds per wave per stage call (2x A-seg, 1x B-seg)
    auto stage = [&](int buf, int k0) {
        const short* Ak; const short* Bk; int kk, ld;
        if (k0 < K1) { Ak = A1; Bk = B1; kk = k0;      ld = K1; }
        else         { Ak = A2; Bk = B2; kk = k0 - K1; ld = K2; }
#pragma unroll
        for (int i = 0; i < 2; ++i) {
            int seg = w * 2 + i;                     // 16 A-segs of 16 rows
            int row = seg * 16 + rs;
            int c8  = cs ^ ((row + (row >> 2)) & 3);
            const short* ga = Ak + (size_t)(row0 + row) * ld + kk + c8 * 8;
            short* la = &sA[buf][seg * 512 + lane * 8];
            __builtin_amdgcn_global_load_lds((const __attribute__((address_space(1))) void*)ga,
                                             (__attribute__((address_space(3))) void*)la, 16, 0, 0);
        }
        {
            int row = w * 16 + rs;                   // 8 B-segs of 16 rows
            int c8  = cs ^ ((row + (row >> 2)) & 3);
            const short* gb = Bk + (size_t)(col0 + row) * ld + kk + c8 * 8;
            short* lb = &sB[buf][w * 512 + lane * 8];
            __builtin_amdgcn_global_load_lds((const __attribute__((address_space(1))) void*)gb,
                                             (__attribute__((address_space(3))) void*)lb, 16, 0, 0);
        }
    };

    stage(0, 0);
    stage(1, 32);                  // 6 loads in flight; KK >= 64 guaranteed
    int cur = 0;
    for (int t = 0; t < nsteps; ++t) {
        // wait for group t (oldest); keep the newer group in flight
        if (t + 1 < nsteps) asm volatile("s_waitcnt vmcnt(3)" ::: "memory");
        else                asm volatile("s_waitcnt vmcnt(0)" ::: "memory");
        __builtin_amdgcn_s_barrier();          // all waves: buf[cur] ready
        asm volatile("" ::: "memory");

        s16x8 af[4], bg[4];
        {
            const int rl = lane & 15;
            const int cw = lane >> 4;
#pragma unroll
            for (int m = 0; m < 4; ++m) {
                int r  = wr * 64 + m * 16 + rl;
                int sl = cw ^ ((r + (r >> 2)) & 3);
                af[m] = *(const s16x8*)(&sA[cur][r * 32 + sl * 8]);
                int c  = wc * 64 + m * 16 + rl;
                int sc = cw ^ ((c + (c >> 2)) & 3);
                bg[m] = *(const s16x8*)(&sB[cur][c * 32 + sc * 8]);
            }
        }
        // MFMAs consume all af/bg (compiler interleaves reads+MFMA with
        // fine-grained lgkmcnt); after them this wave's LDS reads are done.
#pragma unroll
        for (int m = 0; m < 4; ++m)
#pragma unroll
            for (int n = 0; n < 4; ++n)
                acc[m][n] = __builtin_amdgcn_mfma_f32_16x16x32_bf16(af[m], bg[n], acc[m][n], 0, 0, 0);

        __builtin_amdgcn_s_barrier();          // all waves done READING buf[cur]
        asm volatile("" ::: "memory");
        if (t + 2 < nsteps) stage(cur, (t + 2) * 32);   // re-stage 2 ahead
        cur ^= 1;
    }

    // C/D layout: col=lane&15, row=(lane>>4)*4+reg
    const int rbase = row0 + rloc;
    if (mode == 2) {
        float bi[4];
#pragma unroll
        for (int gg2 = 0; gg2 < 4; ++gg2) {
            float bb = bhh ? bhh[gg2 * 256 + ch] : 0.f;
            bi[gg2] = bih[gg2 * 256 + ch] + bb;
        }
#pragma unroll
        for (int m = 0; m < 4; ++m) {
#pragma unroll
            for (int r = 0; r < 4; ++r) {
                int row = rbase + m * 16 + r;
                float gi = acc[m][0][r] + bi[0];
                float gf = acc[m][1][r] + bi[1];
                float gg = acc[m][2][r] + bi[2];
                float go = acc[m][3][r] + bi[3];
                size_t idx = (size_t)row * HID + ch;
                float co = c_in ? co_pre[m][r] : 0.f;
                float c2 = fsigm(gf) * co + fsigm(gi) * ftanh(gg);
                float h2 = fsigm(go) * ftanh(c2);
                c_out[idx] = c2;
                h_out[idx] = f2b(h2);
            }
        }
    } else {
        const int cbase = col0 + wc * 64 + l16;
#pragma unroll
        for (int n = 0; n < 4; ++n) {
            int col = cbase + n * 16;
            float ba = bias ? bias[col] : 0.f;
#pragma unroll
            for (int m = 0; m < 4; ++m) {
#pragma unroll
                for (int r = 0; r < 4; ++r) {
                    int row = rbase + m * 16 + r;
                    float v = acc[m][n][r] + ba;
                    size_t idx = (size_t)row * N + col;
                    if (mode == 1) Cb[idx] = f2b(v);
                    else           Cf[idx] = v;
                }
            }
        }
    }
}

// ---------------- fused GATv2 (softmax + aggregate + bias + LN + ELU) -------
// quarter-wave per head; 8-wide gather batching (one exposed latency window
// for deg <= 8, which covers most nodes at avg degree 5).
// xlr: [MP][512] bf16, cols 0..255 = lin_l(x), 256..511 = lin_r(x).
__global__ __launch_bounds__(256) void gat_fused(
    const short* __restrict__ xlr, const int* __restrict__ rowptr,
    const int* __restrict__ esrc, const float* __restrict__ att,
    const float* __restrict__ gb, const float* __restrict__ lg,
    const float* __restrict__ lb, short* __restrict__ outb)
{
    int i    = blockIdx.x * 4 + (threadIdx.x >> 6);
    int lane = threadIdx.x & 63;
    if (i >= NN) return;
    const int cb = (lane >> 4) * 64 + (lane & 15) * 4;   // channel base

    float xr4[4], at4[4];
    {
        s16x4 v = *(const s16x4*)(&xlr[(size_t)i * 512 + 256 + cb]);
#pragma unroll
        for (int j = 0; j < 4; ++j) { xr4[j] = b2f(v[j]); at4[j] = att[cb + j]; }
    }
    float mx = -INFINITY, sm = 0.f;
    float ac[4] = {0.f, 0.f, 0.f, 0.f};

    // process one gathered edge (identical math/order to r23/r24/r25)
    auto process = [&](s16x4 xv) {
        float xs[4], pl = 0.f;
#pragma unroll
        for (int j = 0; j < 4; ++j) {
            xs[j] = b2f(xv[j]);
            float v = xs[j] + xr4[j];
            v = (v >= 0.f) ? v : 0.2f * v;
            pl += v * at4[j];
        }
#pragma unroll
        for (int o = 1; o < 16; o <<= 1) pl += __shfl_xor(pl, o);   // head logit
        float mn = fmaxf(mx, pl);
        float sc = fexp(mx - mn);            // first iter: exp(-inf)=0
        float a  = fexp(pl - mn);
        sm = sm * sc + a;
#pragma unroll
        for (int j = 0; j < 4; ++j) ac[j] = ac[j] * sc + a * xs[j];
        mx = mn;
    };

    int lo = rowptr[i], hi = rowptr[i + 1];   // wave-uniform; deg >= 1
    for (int e0 = lo; e0 < hi; e0 += 8) {
        int n = hi - e0;                      // wave-uniform chunk size
        int s0 = esrc[e0];
        int s1 = (n > 1) ? esrc[e0 + 1] : s0;
        int s2 = (n > 2) ? esrc[e0 + 2] : s0;
        int s3 = (n > 3) ? esrc[e0 + 3] : s0;
        int s4 = (n > 4) ? esrc[e0 + 4] : s0;
        int s5 = (n > 5) ? esrc[e0 + 5] : s0;
        int s6 = (n > 6) ? esrc[e0 + 6] : s0;
        int s7 = (n > 7) ? esrc[e0 + 7] : s0;
        s16x4 x0 = *(const s16x4*)(&xlr[(size_t)s0 * 512 + cb]);
        s16x4 x1 = *(const s16x4*)(&xlr[(size_t)s1 * 512 + cb]);
        s16x4 x2 = *(const s16x4*)(&xlr[(size_t)s2 * 512 + cb]);
        s16x4 x3 = *(const s16x4*)(&xlr[(size_t)s3 * 512 + cb]);
        s16x4 x4 = *(const s16x4*)(&xlr[(size_t)s4 * 512 + cb]);
        s16x4 x5 = *(const s16x4*)(&xlr[(size_t)s5 * 512 + cb]);
        s16x4 x6 = *(const s16x4*)(&xlr[(size_t)s6 * 512 + cb]);
        s16x4 x7 = *(const s16x4*)(&xlr[(size_t)s7 * 512 + cb]);
        process(x0);
        if (n > 1) process(x1);
        if (n > 2) process(x2);
        if (n > 3) process(x3);
        if (n > 4) process(x4);
        if (n > 5) process(x5);
        if (n > 6) process(x6);
        if (n > 7) process(x7);
    }

    // y = ac/sm (+ gat bias), then LayerNorm(256) + ELU, write bf16
    float val[4], s1v = 0.f, s2v = 0.f;
    float ism = frcp(sm);
#pragma unroll
    for (int j = 0; j < 4; ++j) {
        float v = ac[j] * ism + gb[cb + j];
        val[j] = v; s1v += v; s2v += v * v;
    }
    s1v = wsum64(s1v); s2v = wsum64(s2v);
    float mean = s1v * (1.f / 256.f);
    float var  = s2v * (1.f / 256.f) - mean * mean;
    float inv  = rsqrtf(var + 1e-5f);
    s16x4 ov;
#pragma unroll
    for (int j = 0; j < 4; ++j) {
        float v = (val[j] - mean) * inv * lg[cb + j] + lb[cb + j];
        v = (v > 0.f) ? v : (fexp(v) - 1.f);
        ov[j] = f2b(v);
    }
    *(s16x4*)(&outb[(size_t)i * HID + cb]) = ov;
}

// ---------------- LayerNorm (+act) for the MLP head -------------------------
__global__ __launch_bounds__(256) void ln_act_kernel(
    const float* __restrict__ in, const float* __restrict__ gamma,
    const float* __restrict__ beta, float* __restrict__ outf,
    short* __restrict__ outb, int width, int act)
{
    int row = blockIdx.x;
    const float* ip = in + (size_t)row * width;
    float vals[3];
    float s = 0.f, ss = 0.f;
    int nw = width >> 8;
    for (int i = 0; i < nw; ++i) {
        int c = threadIdx.x + (i << 8);
        float v = ip[c];
        vals[i] = v; s += v; ss += v * v;
    }
#pragma unroll
    for (int off = 32; off > 0; off >>= 1) {
        s  += __shfl_down(s, off);
        ss += __shfl_down(ss, off);
    }
    __shared__ float sh[8];
    int wv = threadIdx.x >> 6, lane = threadIdx.x & 63;
    if (lane == 0) { sh[wv] = s; sh[4 + wv] = ss; }
    __syncthreads();
    if (threadIdx.x == 0) {
        sh[0] = sh[0] + sh[1] + sh[2] + sh[3];
        sh[4] = sh[4] + sh[5] + sh[6] + sh[7];
    }
    __syncthreads();
    float mean = sh[0] / width;
    float var  = sh[4] / width - mean * mean;
    float inv  = rsqrtf(var + 1e-5f);
    for (int i = 0; i < nw; ++i) {
        int c = threadIdx.x + (i << 8);
        float v = (vals[i] - mean) * inv * gamma[c] + beta[c];
        if (act == 1) v = fmaxf(v, 0.f);
        if (outb) outb[(size_t)row * width + c] = f2b(v);
        else      outf[(size_t)row * width + c] = v;
    }
}

// ---------------- sorted-batch mean pool (precomputed bounds) ---------------
__global__ __launch_bounds__(256) void pool_mean(
    const short* __restrict__ h, const int* __restrict__ gbnd,
    short* __restrict__ poolb)
{
    int b    = blockIdx.x * 4 + (threadIdx.x >> 6);
    int lane = threadIdx.x & 63;
    if (b >= BG) return;
    int lo = gbnd[b], hi = gbnd[b + 1];
    float acc[HEADS] = {0.f, 0.f, 0.f, 0.f};
    for (int r = lo; r < hi; ++r)
#pragma unroll
        for (int hh = 0; hh < HEADS; ++hh)
            acc[hh] += b2f(h[(size_t)r * HID + hh * 64 + lane]);
    float inv = 1.f / fmaxf((float)(hi - lo), 1.f);
#pragma unroll
    for (int hh = 0; hh < HEADS; ++hh)
        poolb[(size_t)b * HID + hh * 64 + lane] = f2b(acc[hh] * inv);
}

// ---------------------------------------------------------------------------
extern "C" void kernel_launch(void* const* d_in, const int* in_sizes, int n_in,
                              void* d_out, int out_size, void* d_ws, size_t ws_size,
                              hipStream_t stream)
{
    (void)in_sizes; (void)n_in; (void)out_size; (void)ws_size;
    const float* x      = (const float*)d_in[0];
    const int*   ei     = (const int*)d_in[1];
    const int*   batch  = (const int*)d_in[2];
    const float* lin0_w = (const float*)d_in[4];
    const float* lin0_b = (const float*)d_in[5];
    const float* r0_wih = (const float*)d_in[6];
    const float* r0_bih = (const float*)d_in[8];
    const float* r0_bhh = (const float*)d_in[9];
    const float* mh1_w  = (const float*)d_in[46];
    const float* mh1_b  = (const float*)d_in[47];
    const float* ln1_g  = (const float*)d_in[48];
    const float* ln1_b  = (const float*)d_in[49];
    const float* mh2_w  = (const float*)d_in[50];
    const float* mh2_b  = (const float*)d_in[51];
    const float* ln2_g  = (const float*)d_in[52];
    const float* ln2_b  = (const float*)d_in[53];
    float* out = (float*)d_out;

    // ---- workspace bump allocation ----
    char* wsb = (char*)d_ws;
    auto alloc = [&](size_t bytes) -> void* {
        void* p = (void*)wsb;
        wsb += (bytes + 255) & ~(size_t)255;
        return p;
    };
    const size_t NH = (size_t)MP * HID;
    float* cb   = (float*)alloc(NH * 4);          // LSTM cell state f32
    short* hA   = (short*)alloc(NH * 2);          // h ping
    short* hB   = (short*)alloc(NH * 2);          // h pong
    short* ybb  = (short*)alloc(NH * 2);          // GAT-out / LSTM-input bf16
    short* xlr  = (short*)alloc((size_t)MP * 512 * 2);  // [xl|xr] bf16
    int*   deg    = (int*)alloc((size_t)NN * 4);
    int*   rowptr = (int*)alloc((size_t)(NN + 1) * 4);
    int*   cursor = (int*)alloc((size_t)NN * 4);
    int*   esrc   = (int*)alloc((size_t)EP * 4);
    int*   bsum   = (int*)alloc((size_t)SCB * 4);
    int*   bpre   = (int*)alloc((size_t)SCB * 4);
    int*   gbnd   = (int*)alloc((size_t)(BG + 1) * 4);
    // weights bf16
    short* w_r0f  = (short*)alloc((size_t)G4H * KP0 * 2);  // folded lin0+rnn0
    float* b_r0   = (float*)alloc((size_t)G4H * 4);        // folded bias
    short* w_lr[3]; short* w_ih[3]; short* w_hh[3]; float* blr[3];
    for (int l = 0; l < 3; ++l) {
        int Kp = (l == 0) ? KP0 : 256;
        w_lr[l] = (short*)alloc((size_t)512 * Kp * 2);
        w_ih[l] = (short*)alloc((size_t)G4H * 256 * 2);
        w_hh[l] = (short*)alloc((size_t)G4H * 256 * 2);
        blr[l]  = (float*)alloc(512 * 4);
    }
    short* w_m1 = (short*)alloc((size_t)NH1 * 256 * 2);
    short* w_m2 = (short*)alloc((size_t)NH2 * NH1 * 2);
    // xb (layer-0 padded input) with head temps aliased over it (head runs
    // only after xb is dead)
    short* xb = (short*)alloc((size_t)MP * KP0 * 2);   // 64 MB
    float* z1    = (float*)xb;                          // BG*NH1 f32 (8.4MB)
    short* z1b   = (short*)(z1 + (size_t)BG * NH1);     // BG*NH1 bf16
    short* poolb = z1b + (size_t)BG * NH1;              // BG*HID bf16

    // mode 0/1 GEMM; 1-D grid with XCD swizzle (requires (M/256)%8==0)
    auto G = [&](const short* A, const short* B, int K, const float* bias,
                 float* Cf, short* Cbb, int M, int N, int mode) {
        int nrp = M / 256, nct = N / 128;
        mfma_gemm<<<dim3(nrp * nct), dim3(512), 0, stream>>>(
            A, B, K, nullptr, nullptr, 0, bias,
            nullptr, nullptr, nullptr, nullptr, nullptr, Cf, Cbb, N, mode, nct);
    };
    // mode 2 LSTM GEMM (dual-source)
    auto GL = [&](const short* A1, const short* B1, int K1,
                  const short* A2, const short* B2, int K2,
                  const float* bih, const float* bhh,
                  const float* ci, float* co, short* ho) {
        mfma_gemm<<<dim3((MP / 256) * 8), dim3(512), 0, stream>>>(
            A1, B1, K1, A2, B2, K2, nullptr,
            bih, bhh, ci, co, ho, nullptr, nullptr, G4H, 2, 8);
    };

    // ---- conversions: x pad-convert (+deg zero), batched weights, folds ----
    conv_x<<<dim3(MP / 8), dim3(256), 0, stream>>>(x, xb, deg);

    CPack cp; int nd = 0;
    auto addc = [&](const float* s, short* d, int rsrc, int rdst, int Ks, int Kd) {
        cp.d[nd++] = CDesc{ s, d, rdst, Ks, Kd, rsrc, 0 };
    };
    auto addg = [&](const float* s, short* d) {
        cp.d[nd++] = CDesc{ s, d, G4H, 256, 256, G4H, 1 };
    };
    for (int l = 0; l < 3; ++l) {
        int base = 10 + 12 * l;
        int K  = (l == 0) ? FIN : 256;
        int Kp = (l == 0) ? KP0 : 256;
        addc((const float*)d_in[base + 0], w_lr[l], 256, 256, K, Kp);
        addc((const float*)d_in[base + 2], w_lr[l] + (size_t)256 * Kp, 256, 256, K, Kp);
        addg((const float*)d_in[base + 8], w_ih[l]);
        addg((const float*)d_in[base + 9], w_hh[l]);
    }
    addc(mh1_w, w_m1, NH1, NH1, 256, 256);
    addc(mh2_w, w_m2, NH2, NH2, NH1, NH1);
    conv_pack<<<dim3(64, nd), dim3(256), 0, stream>>>(cp, nd);

    fold_w<<<dim3(G4H), dim3(320), 0, stream>>>(r0_wih, lin0_w, w_r0f);
    fold_b<<<dim3(4), dim3(256), 0, stream>>>(r0_wih, lin0_b, r0_bih, r0_bhh, b_r0);

    BPack bp;
    for (int l = 0; l < 3; ++l) {
        int base = 10 + 12 * l;
        bp.a[l] = (const float*)d_in[base + 1];
        bp.b[l] = (const float*)d_in[base + 3];
        bp.dst[l] = blr[l];
    }
    concat_pack<<<dim3(6), dim3(256), 0, stream>>>(bp);
    pool_bounds<<<dim3((BG + 256) / 256), dim3(256), 0, stream>>>(batch, gbnd);

    // ---- CSR build (deg zeroed by conv_x) ----
    edge_hist<<<dim3((EP + 255) / 256), dim3(256), 0, stream>>>(ei, deg);
    scan_part<<<dim3(SCB), dim3(256), 0, stream>>>(deg, bsum);
    scan_tops<<<dim3(1), dim3(512), 0, stream>>>(bsum, bpre, rowptr);
    scan_fill<<<dim3(SCB), dim3(256), 0, stream>>>(deg, bpre, rowptr, cursor);
    edge_fill<<<dim3((EP + 255) / 256), dim3(256), 0, stream>>>(ei, rowptr, cursor, esrc);

    // ---- rnn0 LSTM directly from xb (folded weights; h=c=0 start) ----
    GL(xb, w_r0f, KP0, nullptr, nullptr, 0, b_r0, nullptr, nullptr, cb, hA);

    // ---- 3x (GATv2 -> LN+ELU -> LSTM) ----
    short* hprev = hA;
    short* hnext = hB;
    for (int l = 0; l < 3; ++l) {
        int base = 10 + 12 * l;
        const float* att = (const float*)d_in[base + 4];
        const float* gb  = (const float*)d_in[base + 5];
        const float* lg  = (const float*)d_in[base + 6];
        const float* lb  = (const float*)d_in[base + 7];
        const float* bih = (const float*)d_in[base + 10];
        const float* bhh = (const float*)d_in[base + 11];
        const short* Ain = (l == 0) ? xb : hprev;
        int K = (l == 0) ? KP0 : 256;

        G(Ain, w_lr[l], K, blr[l], nullptr, xlr, MP, 512, 1);
        gat_fused<<<dim3((NN + 3) / 4), dim3(256), 0, stream>>>(
            xlr, rowptr, esrc, att, gb, lg, lb, ybb);
        GL(ybb, w_ih[l], 256, hprev, w_hh[l], 256, bih, bhh, cb, cb, hnext);
        short* t = hprev; hprev = hnext; hnext = t;
    }

    // ---- mean pool (precomputed bounds) + MLP head ----
    pool_mean<<<dim3((BG + 3) / 4), dim3(256), 0, stream>>>(hprev, gbnd, poolb);
    G(poolb, w_m1, 256, mh1_b, z1, nullptr, BG, NH1, 0);
    ln_act_kernel<<<dim3(BG), dim3(256), 0, stream>>>(z1, ln1_g, ln1_b, nullptr, z1b, NH1, 1);
    G(z1b, w_m2, NH1, mh2_b, out, nullptr, BG, NH2, 0);
    ln_act_kernel<<<dim3(BG), dim3(256), 0, stream>>>(out, ln2_g, ln2_b, out, nullptr, NH2, 0);
}